// Round 3
// baseline (894.649 us; speedup 1.0000x reference)
//
#include <hip/hip_runtime.h>
#include <hip/hip_bf16.h>

using bf16 = __hip_bfloat16;
using short8 = __attribute__((ext_vector_type(8))) short;   // 8 bf16 (4 VGPRs)
using floatx4 = __attribute__((ext_vector_type(4))) float;  // 4 fp32 acc

#define NSEG 4
#define HID 768
#define INDIM 1536
#define NQKV 2304
#define NHEADS 8
#define HD 96

// fp32 -> bf16 bits, round-to-nearest-even
__device__ inline unsigned short f2b(float v) {
  union { float f; unsigned u; } c; c.f = v;
  unsigned r = c.u + 0x7FFF + ((c.u >> 16) & 1);
  return (unsigned short)(r >> 16);
}

// load 8 consecutive fp32 elements, convert to 8 bf16 packed in uint4
__device__ inline uint4 ld8f32_bf(const float* p) {
  float4 a = *(const float4*)p;
  float4 b = *(const float4*)(p + 4);
  union { uint4 u; unsigned short s[8]; } r;
  r.s[0] = f2b(a.x); r.s[1] = f2b(a.y); r.s[2] = f2b(a.z); r.s[3] = f2b(a.w);
  r.s[4] = f2b(b.x); r.s[5] = f2b(b.y); r.s[6] = f2b(b.z); r.s[7] = f2b(b.w);
  return r.u;
}

// ---------------------------------------------------------------------------
// Tiled transpose + fp32->bf16: src K x C fp32 row-major, dst C x K bf16.
// ---------------------------------------------------------------------------
__global__ __launch_bounds__(256) void transpose_w(
    const float* __restrict__ src, bf16* __restrict__ dst, int K, int C) {
  __shared__ unsigned short tile[32][33];
  const int c0 = blockIdx.x * 32, k0 = blockIdx.y * 32;
  const int tx = threadIdx.x, ty = threadIdx.y;  // 32 x 8
#pragma unroll
  for (int i = 0; i < 4; ++i)
    tile[ty + 8 * i][tx] = f2b(src[(size_t)(k0 + ty + 8 * i) * C + c0 + tx]);
  __syncthreads();
  unsigned short* d = (unsigned short*)dst;
#pragma unroll
  for (int i = 0; i < 4; ++i)
    d[(size_t)(c0 + ty + 8 * i) * K + k0 + tx] = tile[tx][ty + 8 * i];
}

// ---------------------------------------------------------------------------
// GEMM1: QKV[m][c] = sum_e Xs[m][e] * Wqkv[e][c];  m = r*4+n, e = p*64+d.
// A gathered from fp32 x (B,T,H,W,D), converted to bf16 in staging.
// wT = Wqkv^T [2304][1536] bf16. 128x128 tile, 4 waves, 4x4 mfma 16x16x32.
// ---------------------------------------------------------------------------
__global__ __launch_bounds__(256, 2) void gemm_qkv(
    const float* __restrict__ x, const bf16* __restrict__ wT,
    bf16* __restrict__ qkv) {
  constexpr int LDA = 40;  // 32->40 shorts: <=2-way LDS aliasing (free)
  __shared__ short As[128 * LDA];
  __shared__ short Bs[128 * LDA];
  const int tid = threadIdx.x;
  const int n0 = blockIdx.x * 128;
  const int m0 = blockIdx.y * 128;
  const int lane = tid & 63, wave = tid >> 6;
  const int wm = (wave >> 1) * 64, wn = (wave & 1) * 64;
  const int l15 = lane & 15, quad = lane >> 4;
  floatx4 acc[4][4] = {};

  for (int kt = 0; kt < 48; ++kt) {
    const int k0 = kt * 32;
    __syncthreads();
#pragma unroll
    for (int i = 0; i < 2; ++i) {
      const int cid = tid + i * 256;      // 512 8-elem chunks per operand
      const int row = cid >> 2, ch = cid & 3;
      // A gather: m = m0+row -> (b, hw, n); k -> (p, d)
      const int m = m0 + row;
      const int n = m & 3, r = m >> 2;
      const int b = r >> 10, hw = r & 1023;
      const int p = k0 >> 6, d = (k0 & 63) + ch * 8;
      const size_t asrc = ((size_t)((b * 96 + n * 24 + p) * 1024 + hw)) * 64 + d;
      *(uint4*)&As[row * LDA + ch * 8] = ld8f32_bf(x + asrc);
      // B: wT row (n0+row), contiguous k
      const size_t bsrc = (size_t)(n0 + row) * INDIM + k0 + ch * 8;
      *(uint4*)&Bs[row * LDA + ch * 8] =
          *(const uint4*)((const unsigned short*)wT + bsrc);
    }
    __syncthreads();
    short8 af[4], bf[4];
#pragma unroll
    for (int t = 0; t < 4; ++t) {
      af[t] = *(const short8*)&As[(wm + t * 16 + l15) * LDA + quad * 8];
      bf[t] = *(const short8*)&Bs[(wn + t * 16 + l15) * LDA + quad * 8];
    }
#pragma unroll
    for (int ti = 0; ti < 4; ++ti)
#pragma unroll
      for (int tj = 0; tj < 4; ++tj)
        acc[ti][tj] = __builtin_amdgcn_mfma_f32_16x16x32_bf16(
            af[ti], bf[tj], acc[ti][tj], 0, 0, 0);
  }
  // epilogue: C/D layout col=lane&15, row=quad*4+reg
#pragma unroll
  for (int ti = 0; ti < 4; ++ti)
#pragma unroll
    for (int tj = 0; tj < 4; ++tj)
#pragma unroll
      for (int reg = 0; reg < 4; ++reg) {
        const int row = m0 + wm + ti * 16 + quad * 4 + reg;
        const int col = n0 + wn + tj * 16 + l15;
        qkv[(size_t)row * NQKV + col] = __float2bfloat16(acc[ti][tj][reg]);
      }
}

// ---------------------------------------------------------------------------
// Attention per row r: RoPE(q,k), per-head 4x4 softmax, O = attn @ v (bf16).
// ---------------------------------------------------------------------------
__global__ __launch_bounds__(256) void attn_kernel(
    const bf16* __restrict__ qkv, const float* __restrict__ fcos,
    const float* __restrict__ fsin, bf16* __restrict__ obuf) {
  constexpr int SF_LD = 2312;  // pad 2304->2312 (bank offset 8 per row)
  __shared__ float sf[NSEG][SF_LD];  // [n][0:768)=q [768:1536)=k [1536:2304)=v
  __shared__ float ssc[NHEADS][NSEG][NSEG];
  __shared__ float sat[NHEADS][NSEG][NSEG];
  const int r = blockIdx.x;
  const int tid = threadIdx.x;
  const bf16* base = qkv + (size_t)r * NSEG * NQKV;

  for (int cid = tid; cid < (NSEG * NQKV) / 8; cid += 256) {
    const int n = cid / (NQKV / 8);
    const int c = (cid % (NQKV / 8)) * 8;
    uint4 u = *(const uint4*)(base + (size_t)n * NQKV + c);
    const bf16* h = reinterpret_cast<const bf16*>(&u);
#pragma unroll
    for (int j = 0; j < 8; ++j) sf[n][c + j] = __bfloat162float(h[j]);
  }
  __syncthreads();

  // RoPE on q and k
  for (int idx = tid; idx < NSEG * (HID / 2); idx += 256) {
    const int n = idx / (HID / 2), j = idx % (HID / 2);
    const float c = fcos[n * (HID / 2) + j];
    const float s = fsin[n * (HID / 2) + j];
    float q0 = sf[n][2 * j], q1 = sf[n][2 * j + 1];
    sf[n][2 * j] = q0 * c - q1 * s;
    sf[n][2 * j + 1] = q0 * s + q1 * c;
    float k0 = sf[n][HID + 2 * j], k1 = sf[n][HID + 2 * j + 1];
    sf[n][HID + 2 * j] = k0 * c - k1 * s;
    sf[n][HID + 2 * j + 1] = k0 * s + k1 * c;
  }
  __syncthreads();

  // scores: 8 heads x 4 x 4 dots of length 96
  if (tid < 128) {
    const int h = tid >> 4, n = (tid >> 2) & 3, m = tid & 3;
    const float* qp = &sf[n][h * HD];
    const float* kp = &sf[m][HID + h * HD];
    float s = 0.f;
#pragma unroll 8
    for (int i = 0; i < HD; ++i) s += qp[i] * kp[i];
    ssc[h][n][m] = s * 0.10206207261596575f;  // 1/sqrt(96)
  }
  __syncthreads();

  if (tid < 32) {
    const int h = tid >> 2, n = tid & 3;
    float mx = ssc[h][n][0];
#pragma unroll
    for (int m = 1; m < 4; ++m) mx = fmaxf(mx, ssc[h][n][m]);
    float e[4], sum = 0.f;
#pragma unroll
    for (int m = 0; m < 4; ++m) { e[m] = __expf(ssc[h][n][m] - mx); sum += e[m]; }
    const float inv = 1.f / sum;
#pragma unroll
    for (int m = 0; m < 4; ++m) sat[h][n][m] = e[m] * inv;
  }
  __syncthreads();

  for (int idx = tid; idx < NSEG * HID; idx += 256) {
    const int n = idx / HID, c = idx % HID, h = c / HD;
    float s = 0.f;
#pragma unroll
    for (int m = 0; m < 4; ++m) s += sat[h][n][m] * sf[m][2 * HID + c];
    obuf[((size_t)r * NSEG + n) * HID + c] = __float2bfloat16(s);
  }
}

// ---------------------------------------------------------------------------
// GEMM2: out = O @ Wo + bo, fused scatter into (B,T,H,W,D) fp32 output.
//   A = obuf [32768][768] bf16, wT = Wo^T [1536][768] bf16, bo fp32.
// ---------------------------------------------------------------------------
__global__ __launch_bounds__(256, 2) void gemm_out(
    const bf16* __restrict__ A, const bf16* __restrict__ wT,
    const float* __restrict__ bo, float* __restrict__ out) {
  constexpr int LDA = 40;
  __shared__ short As[128 * LDA];
  __shared__ short Bs[128 * LDA];
  const int tid = threadIdx.x;
  const int n0 = blockIdx.x * 128;
  const int m0 = blockIdx.y * 128;
  const int lane = tid & 63, wave = tid >> 6;
  const int wm = (wave >> 1) * 64, wn = (wave & 1) * 64;
  const int l15 = lane & 15, quad = lane >> 4;
  floatx4 acc[4][4] = {};

  for (int kt = 0; kt < 24; ++kt) {
    const int k0 = kt * 32;
    __syncthreads();
#pragma unroll
    for (int i = 0; i < 2; ++i) {
      const int cid = tid + i * 256;
      const int row = cid >> 2, ch = cid & 3;
      const size_t asrc = (size_t)(m0 + row) * HID + k0 + ch * 8;
      *(uint4*)&As[row * LDA + ch * 8] =
          *(const uint4*)((const unsigned short*)A + asrc);
      const size_t bsrc = (size_t)(n0 + row) * HID + k0 + ch * 8;
      *(uint4*)&Bs[row * LDA + ch * 8] =
          *(const uint4*)((const unsigned short*)wT + bsrc);
    }
    __syncthreads();
    short8 af[4], bf[4];
#pragma unroll
    for (int t = 0; t < 4; ++t) {
      af[t] = *(const short8*)&As[(wm + t * 16 + l15) * LDA + quad * 8];
      bf[t] = *(const short8*)&Bs[(wn + t * 16 + l15) * LDA + quad * 8];
    }
#pragma unroll
    for (int ti = 0; ti < 4; ++ti)
#pragma unroll
      for (int tj = 0; tj < 4; ++tj)
        acc[ti][tj] = __builtin_amdgcn_mfma_f32_16x16x32_bf16(
            af[ti], bf[tj], acc[ti][tj], 0, 0, 0);
  }
  // epilogue: bias + scatter to (B,T,H,W,D) fp32: t = n*24+p
#pragma unroll
  for (int ti = 0; ti < 4; ++ti)
#pragma unroll
    for (int tj = 0; tj < 4; ++tj)
#pragma unroll
      for (int reg = 0; reg < 4; ++reg) {
        const int row = m0 + wm + ti * 16 + quad * 4 + reg;
        const int col = n0 + wn + tj * 16 + l15;
        const float v = acc[ti][tj][reg] + bo[col];
        const int r = row >> 2, n = row & 3;
        const int b = r >> 10, hw = r & 1023;
        const int p = col >> 6, d = col & 63;
        const size_t dst =
            ((size_t)((b * 96 + n * 24 + p) * 1024 + hw)) * 64 + d;
        out[dst] = v;
      }
}

// ---------------------------------------------------------------------------
extern "C" void kernel_launch(void* const* d_in, const int* in_sizes, int n_in,
                              void* d_out, int out_size, void* d_ws,
                              size_t ws_size, hipStream_t stream) {
  const float* x = (const float*)d_in[0];     // (8,96,32,32,64) fp32
  const float* fcos = (const float*)d_in[1];  // (4,384) fp32
  const float* fsin = (const float*)d_in[2];  // (4,384) fp32
  const float* Wq = (const float*)d_in[3];    // (1536,768) fp32
  const float* Wk = (const float*)d_in[4];
  const float* Wv = (const float*)d_in[5];
  const float* Wo = (const float*)d_in[6];    // (768,1536) fp32
  const float* bo = (const float*)d_in[7];    // (1536,) fp32
  float* out = (float*)d_out;                 // (8,96,32,32,64) fp32

  char* ws = (char*)d_ws;
  bf16* wqkvT = (bf16*)ws;                        // 2304*1536*2 = 7,077,888 B
  bf16* woT = (bf16*)(ws + 7077888);              // 1536*768*2  = 2,359,296 B
  bf16* qkv = (bf16*)(ws + 9437184);              // 32768*2304*2 = 150,994,944 B
  bf16* obuf = (bf16*)(ws + 160432128);           // 32768*768*2  = 50,331,648 B

  dim3 tb(32, 8);
  transpose_w<<<dim3(24, 48), tb, 0, stream>>>(Wq, wqkvT, INDIM, HID);
  transpose_w<<<dim3(24, 48), tb, 0, stream>>>(Wk, wqkvT + (size_t)HID * INDIM, INDIM, HID);
  transpose_w<<<dim3(24, 48), tb, 0, stream>>>(Wv, wqkvT + (size_t)2 * HID * INDIM, INDIM, HID);
  transpose_w<<<dim3(48, 24), tb, 0, stream>>>(Wo, woT, HID, INDIM);

  gemm_qkv<<<dim3(18, 256), 256, 0, stream>>>(x, wqkvT, qkv);
  attn_kernel<<<8192, 256, 0, stream>>>(qkv, fcos, fsin, obuf);
  gemm_out<<<dim3(12, 256), 256, 0, stream>>>(obuf, woT, bo, out);
}